// Round 15
// baseline (166.370 us; speedup 1.0000x reference)
//
#include <hip/hip_runtime.h>
#include <math.h>

// Focal_loss2 — single fused dispatch. FINAL (R13, best of 14 rounds):
// z-paired rolling y-march + XCD swizzle + all-non-temporal loads.
// Session law (R4-R14): dur ~= k(concurrency) x requests/elem; k~=50 µs at
// >=4 waves/CU with NT loads. R13 sits at the joint optimum: 0.875 req/elem
// at 4 waves/CU beats 0.719 req/elem at 2.6 waves/CU (R14: 48 µs vs 44).
// Exhausted levers (all measured): request count (R12/R14), concurrency
// (R5/R6), L1 64KB-stride aliasing (NT, +8%), XCD locality (swizzle, +15%),
// LDS staging sync/async (R3/R9, regressed), shuffle plane-sharing and
// predicated gt (R11, regressed on dependency structure).
//   neg: w = sigmoid(x)^2 * (gt==-1) * (x is 3x3x3 local max); loss += softplus(x)*w
//        local-max test in logit space (monotone sigmoid; absmax 0.0 R3-R14)
//   pos: 64 coords/batch/level gather; w1=(1-sigmoid)^2; per-(b,tag) min of w1
// ws (floats): [0]=lossneg_a [1]=wneg_a [2]=lossneg_b [3]=wneg_b
//              [4]=losspos_a [5]=cntpos_a [6]=losspos_b [7]=cntpos_b [8]=block counter
// out: [0]=cls_loss_pos [1]=cls_loss_neg [2]=count_pos [3]=count_neg
//      [4]=wsum_pos [5]=wsum_neg [6..37]=pred_prob_min[2][B=2][T=8]

#define NBLK_A 512    // 4 vol x 8 z-groups(16 z) x 16 y-chunks(8 y)
#define NBLK_B 64     // 4 vol x 2 z-groups(32 z) x  8 y-chunks(8 y)
#define NBLK_TOTAL (NBLK_A + NBLK_B + 1)

using f4 = __attribute__((ext_vector_type(4))) float;

__device__ __forceinline__ float fmax3(float a, float b, float c) {
    return fmaxf(a, fmaxf(b, c));
}

__device__ __forceinline__ f4 fmax3v(f4 a, f4 b, f4 c) {
    f4 r;
    r.x = fmax3(a.x, b.x, c.x); r.y = fmax3(a.y, b.y, c.y);
    r.z = fmax3(a.z, b.z, c.z); r.w = fmax3(a.w, b.w, c.w);
    return r;
}

// Emit one output quad. x-halo via wave shuffle (xq in low lane bits; group
// edges overridden by the clamp rule).
template <int XQ>
__device__ __forceinline__ void emit_row(
    const f4 zw0, const f4 zw1, const f4 zw2, const f4 c, const f4 g,
    int xq, float& loss, float& wsum)
{
    f4 cz = fmax3v(zw0, zw1, zw2);                    // y-fold
    float lco = __shfl_up(cz.w, 1);   if (xq == 0)      lco = cz.x;
    float rco = __shfl_down(cz.x, 1); if (xq == XQ - 1) rco = cz.w;
    float ms[4] = {fmax3(lco, cz.x, cz.y), fmax3(cz.x, cz.y, cz.z),
                   fmax3(cz.y, cz.z, cz.w), fmax3(cz.z, cz.w, rco)};
    float cs[4] = {c.x, c.y, c.z, c.w};
    float gs[4] = {g.x, g.y, g.z, g.w};
#pragma unroll
    for (int k = 0; k < 4; ++k) {
        if (gs[k] == -1.0f && ms[k] == cs[k]) {
            float e = __expf(cs[k]);                  // e^x
            float u = __builtin_amdgcn_rcpf(1.0f + e);
            float sc = e * u;                         // sigmoid(x)
            float wv = sc * sc;
            wsum += wv;
            loss += (-__logf(u)) * wv;                // softplus(x)
        }
    }
}

// One thread: fixed (x-quad, z-pair). Marches y0-1..y0+8 (10 rows, clamped),
// emitting 8 y-rows at BOTH z and z+1 from 4 planes z-1..z+2 (z-pairing).
// All loads non-temporal (bypass the set-aliased L1). Boundary: index
// clamping duplicates an in-window value -> max unchanged.
template <int D, int LOG2D, int XQ>
__device__ __forceinline__ void neg_march2(
    const float* __restrict__ logits, const float* __restrict__ gt,
    int vol, int z, int y0, int xq, float& loss, float& wsum)
{
    const int x0 = xq << 2;
    const float* vb = logits + (vol << (3 * LOG2D));
    const int zm = z > 0 ? z - 1 : 0;              // z+1 <= D-1 by construction
    const int zq = z + 2 < D ? z + 2 : D - 1;
    const float* p0 = vb + (zm << (2 * LOG2D));
    const float* p1 = vb + (z << (2 * LOG2D));
    const float* p2 = vb + ((z + 1) << (2 * LOG2D));
    const float* p3 = vb + (zq << (2 * LOG2D));
    const float* g1 = gt + (vol << (3 * LOG2D)) + (z << (2 * LOG2D));
    const float* g2 = g1 + (1 << (2 * LOG2D));

    f4 za[3], zb[3];   // rings: z-folded col max for output z / z+1
    f4 ca[2], cb[2];   // rings: center raw quads (plane z / z+1)
    f4 ga[2], gb[2];   // rings: gt quads

#pragma unroll
    for (int s = 0; s < 10; ++s) {
        int yy = y0 - 1 + s;
        yy = yy < 0 ? 0 : (yy > D - 1 ? D - 1 : yy);
        const int ro = (yy << LOG2D) + x0;
        f4 r0 = __builtin_nontemporal_load((const f4*)(p0 + ro));
        f4 r1 = __builtin_nontemporal_load((const f4*)(p1 + ro));
        f4 r2 = __builtin_nontemporal_load((const f4*)(p2 + ro));
        f4 r3 = __builtin_nontemporal_load((const f4*)(p3 + ro));
        if (s >= 1 && s <= 8) {       // gt rows: single-use stream
            ga[s & 1] = __builtin_nontemporal_load((const f4*)(g1 + ro));
            gb[s & 1] = __builtin_nontemporal_load((const f4*)(g2 + ro));
        }
        za[s % 3] = fmax3v(r0, r1, r2);
        zb[s % 3] = fmax3v(r1, r2, r3);
        ca[s & 1] = r1;
        cb[s & 1] = r2;
        if (s >= 2) {
            emit_row<XQ>(za[0], za[1], za[2], ca[(s - 1) & 1], ga[(s - 1) & 1],
                         xq, loss, wsum);
            emit_row<XQ>(zb[0], zb[1], zb[2], cb[(s - 1) & 1], gb[(s - 1) & 1],
                         xq, loss, wsum);
        }
    }
}

__global__ __launch_bounds__(256, 4) void fused_kernel(
    const float* __restrict__ la, const float* __restrict__ lb,
    const float* __restrict__ ga, const float* __restrict__ gb,
    const int* __restrict__ conn_a, const int* __restrict__ conn_b,
    const int* __restrict__ coord_a, const int* __restrict__ coord_b,
    float* __restrict__ ws, float* __restrict__ out)
{
    __shared__ float sred[8];
    __shared__ float w1s[128];
    __shared__ float tgf[128];
    const int bid = blockIdx.x;
    const int t = threadIdx.x;
    float loss = 0.0f, wsum = 0.0f;
    int accIdx = -1;

    if (bid < NBLK_A) {
        // level a: D=128. xq = t&31, z-pair = t>>5 (block: 16 z x 8 y).
        // XCD swizzle: xcd = bid&7 owns z-group c (16 z) for all 4 vols.
        accIdx = 0;
        const int c = bid & 7;
        const int g = bid >> 3;        // 0..63
        const int yc = g & 15;         // y fastest
        const int vol = g >> 4;
        neg_march2<128, 7, 32>(la, ga, vol, c * 16 + (t >> 5) * 2, yc * 8,
                               t & 31, loss, wsum);
    } else if (bid < NBLK_A + NBLK_B) {
        // level b: D=64. xq = t&15, z-pair = t>>4 (block: 32 z x 8 y).
        accIdx = 2;
        const int b2 = bid - NBLK_A;
        const int c = b2 & 7;
        const int yc = b2 >> 3;
        const int vol = c >> 1;
        const int zg = c & 1;
        neg_march2<64, 6, 16>(lb, gb, vol, zg * 32 + (t >> 4) * 2, yc * 8,
                              t & 15, loss, wsum);
    } else {
        // pos block: both levels, 128 active threads
        for (int level = 0; level < 2; ++level) {
            const float* logits = level ? lb : la;
            const int* conn = level ? conn_b : conn_a;
            const int* coord = level ? coord_b : coord_a;
            const int D = level ? 64 : 128;
            float li = 0.0f, ci = 0.0f;
            if (t < 128) {
                const int* c4 = coord + t * 4;
                int a = c4[0], zz = c4[1], yy = c4[2], xx = c4[3];
                bool valid = a > -1;
                int aa = valid ? a : 0, z2 = valid ? zz : 0,
                    y2 = valid ? yy : 0, x2 = valid ? xx : 0;
                int b = t >> 6;
                int off = (((b * 2 + aa) * D + z2) * D + y2) * D + x2;
                float lp = logits[off];
                int tag = conn[off];
                float s = 1.0f / (1.0f + expf(lp));   // 1 - sigmoid(lp)
                float w1 = s * s;
                float vf = valid ? 1.0f : 0.0f;
                float sp = fmaxf(-lp, 0.0f) + log1pf(expf(-fabsf(lp)));  // softplus(-lp)
                li = sp * w1 * vf;
                ci = w1 * vf;
                w1s[t] = w1;
                tgf[t] = (float)(valid ? tag : -1);
            }
            for (int o = 32; o; o >>= 1) {
                li += __shfl_down(li, o);
                ci += __shfl_down(ci, o);
            }
            if ((t & 63) == 0) { sred[t >> 6] = li; sred[4 + (t >> 6)] = ci; }
            __syncthreads();
            if (t == 0) {
                atomicAdd(ws + 4 + 2 * level, sred[0] + sred[1] + sred[2] + sred[3]);
                atomicAdd(ws + 5 + 2 * level, sred[4] + sred[5] + sred[6] + sred[7]);
            }
            if (t < 16) {
                int bb = t >> 3, tg = t & 7;
                float mn = INFINITY;
                for (int i = 0; i < 64; ++i) {
                    int j = bb * 64 + i;
                    if (tgf[j] == (float)tg) mn = fminf(mn, w1s[j]);
                }
                out[6 + level * 16 + bb * 8 + tg] = isinf(mn) ? -1.0f : mn;
            }
            __syncthreads();
        }
    }

    if (accIdx >= 0) {
        for (int o = 32; o; o >>= 1) {
            loss += __shfl_down(loss, o);
            wsum += __shfl_down(wsum, o);
        }
        if ((t & 63) == 0) { sred[t >> 6] = loss; sred[4 + (t >> 6)] = wsum; }
        __syncthreads();
        if (t == 0) {
            float L = sred[0] + sred[1] + sred[2] + sred[3];
            float W = sred[4] + sred[5] + sred[6] + sred[7];
            if (L != 0.0f || W != 0.0f) {
                atomicAdd(ws + accIdx, L);
                atomicAdd(ws + accIdx + 1, W);
            }
        }
    }

    // last-block finalize
    if (t == 0) {
        __threadfence();
        unsigned int old = atomicAdd((unsigned int*)(ws + 8), 1u);
        if (old == NBLK_TOTAL - 1) {
            float s0 = atomicAdd(ws + 0, 0.0f);
            float s1 = atomicAdd(ws + 1, 0.0f);
            float s2 = atomicAdd(ws + 2, 0.0f);
            float s3 = atomicAdd(ws + 3, 0.0f);
            float s4 = atomicAdd(ws + 4, 0.0f);
            float s5 = atomicAdd(ws + 5, 0.0f);
            float s6 = atomicAdd(ws + 6, 0.0f);
            float s7 = atomicAdd(ws + 7, 0.0f);
            out[0] = s4 * 2.0f + s6;   // cls_loss_pos (POS_FACTOR {2,1})
            out[1] = s0 * 2.0f + s2;   // cls_loss_neg (NEG_FACTOR {2,1})
            out[2] = s5 + s7;          // count_pos
            out[3] = s1 + s3;          // count_neg
            out[4] = s5 * 2.0f + s7;   // wsum_pos (anchor factor == 1)
            out[5] = s1 * 2.0f + s3;   // wsum_neg
        }
    }
}

extern "C" void kernel_launch(void* const* d_in, const int* in_sizes, int n_in,
                              void* d_out, int out_size, void* d_ws, size_t ws_size,
                              hipStream_t stream) {
    const float* logits_a = (const float*)d_in[0];
    const float* logits_b = (const float*)d_in[1];
    const float* prob_a   = (const float*)d_in[2];
    const float* prob_b   = (const float*)d_in[3];
    const int*   conn_a   = (const int*)d_in[4];
    const int*   conn_b   = (const int*)d_in[5];
    const int*   coord_a  = (const int*)d_in[6];
    const int*   coord_b  = (const int*)d_in[7];
    float* out = (float*)d_out;
    float* ws  = (float*)d_ws;

    hipMemsetAsync(ws, 0, 12 * sizeof(float), stream);
    fused_kernel<<<NBLK_TOTAL, 256, 0, stream>>>(
        logits_a, logits_b, prob_a, prob_b,
        conn_a, conn_b, coord_a, coord_b, ws, out);
}